// Round 2
// baseline (344.876 us; speedup 1.0000x reference)
//
#include <hip/hip_runtime.h>
#include <hip/hip_cooperative_groups.h>

namespace cg = cooperative_groups;

// GCN 2-layer, N=100k, E=3.2M, IN=2, HID=64, OUT=1 (all float32).
// R16 = R14 base (158.8us) with the R15 deg-atomic REVERTED (lesson: 3.2M
// random global atomics = ~100MB HBM write traffic, k_sort 140us) and the
// four post-memset launches FUSED into one cooperative kernel:
//  - phase 1: staged counting sort (proven R14 code, unchanged)
//  - grid.sync()
//  - phase 2: bucket -> LDS pk[] ONCE (union with sort stage, 53KB, 2 blk/CU),
//    LDS histogram, dinv/y kept in REGISTERS (same thread owns node i in all
//    phases) -- dinv never round-trips through global
//  - phase 3: scatter y (edge words from LDS), MLP -> t
//  - phase 4: scatter t (from LDS), out
// Saves 3 launch boundaries (~12us), 2x 12.8MB packed re-reads, dinv/self
// traffic, weight reloads. Fallback: if cooperative launch is rejected
// (graph capture / occupancy), run the exact R14 4-kernel chain.

#define NBUCK 512
#define BSH   196        // nodes per bucket (512*196 = 100352 >= n)
#define RBITS 17         // row bits (n < 131072)
#define RMASK ((1 << RBITS) - 1)
#define CAP   6752       // packed ints per bucket (mean 6250, +6.3 sigma), %4==0
#define SORTB 512
#define SCAPS 24         // staging per (block,bucket): mean 12.2, +3.4 sigma
#define TPS   1024
#define TPB   1024

struct SortSh { int fill[NBUCK]; int gb[NBUCK]; int stage[NBUCK * SCAPS]; }; // 53248B
struct CompSh { int pk[CAP]; float2 acc[BSH]; int hist[BSH];
                float w1a[64], w1b[64], bb1[64], w2[64]; };                  // 30384B
union ShU { SortSh s; CompSh c; };

__device__ __forceinline__ void sort_one(int c, int r, int* fill, int* stage,
                                         int* __restrict__ gcur,
                                         int* __restrict__ packed) {
    int b = (int)((unsigned)c / (unsigned)BSH);   // magic-mul div by 196
    int l = c - b * BSH;
    int w = (l << RBITS) | r;
    int p = atomicAdd(&fill[b], 1);
    if (p < SCAPS) stage[b * SCAPS + p] = w;
    else packed[b * CAP + atomicAdd(&gcur[b], 1)] = w;  // rare spill (rel cursor)
}

__global__ void __launch_bounds__(TPS, 8)
k_fused(const int* __restrict__ row, const int* __restrict__ col,
        const float2* __restrict__ x,
        const float* __restrict__ W1, const float* __restrict__ B1,
        const float* __restrict__ W2, const float* __restrict__ B2,
        int* __restrict__ gcur, int* __restrict__ packed,
        float2* __restrict__ y, float* __restrict__ t,
        float* __restrict__ out, int E, int n) {
    __shared__ ShU u;
    cg::grid_group grid = cg::this_grid();
    const int tid = threadIdx.x, bid = blockIdx.x;

    // ---------- phase 1: staged counting sort by dest bucket ----------
    for (int i = tid; i < NBUCK; i += TPS) u.s.fill[i] = 0;
    __syncthreads();
    {
        const int q = E >> 2;
        const int q0 = (int)((long long)bid * q / SORTB);
        const int q1 = (int)((long long)(bid + 1) * q / SORTB);
        const int4* c4 = (const int4*)col;
        const int4* r4 = (const int4*)row;
        for (int i = q0 + tid; i < q1; i += TPS) {
            int4 c = c4[i], r = r4[i];
            sort_one(c.x, r.x, u.s.fill, u.s.stage, gcur, packed);
            sort_one(c.y, r.y, u.s.fill, u.s.stage, gcur, packed);
            sort_one(c.z, r.z, u.s.fill, u.s.stage, gcur, packed);
            sort_one(c.w, r.w, u.s.fill, u.s.stage, gcur, packed);
        }
        if (bid == SORTB - 1)   // tail if E % 4 != 0
            for (int e = (q << 2) + tid; e < E; e += TPS)
                sort_one(col[e], row[e], u.s.fill, u.s.stage, gcur, packed);
        __syncthreads();
        for (int b = tid; b < NBUCK; b += TPS)
            u.s.gb[b] = b * CAP + atomicAdd(&gcur[b], min(u.s.fill[b], SCAPS));
        __syncthreads();
        const int wid = tid >> 6, lane = tid & 63;
        for (int b = wid; b < NBUCK; b += (TPS >> 6)) {  // per-wave coalesced copy-out
            int cnt = min(u.s.fill[b], SCAPS);           // cnt <= 24 < wave
            if (lane < cnt) packed[u.s.gb[b] + lane] = u.s.stage[b * SCAPS + lane];
        }
    }

    grid.sync();   // packed + gcur globally visible

    // ---------- phase 2: bucket -> LDS, histogram, dinv/y (regs) ----------
    const int base = bid * CAP;
    const int len = gcur[bid];
    const int lq = len >> 2;
    int4* pk4 = (int4*)u.c.pk;
    if (tid < BSH) { u.c.hist[tid] = 0; u.c.acc[tid] = make_float2(0.f, 0.f); }
    if (tid >= 256 && tid < 320) {
        int h = tid - 256;
        u.c.w1a[h] = W1[h];
        u.c.w1b[h] = W1[64 + h];
        u.c.bb1[h] = B1[h];
        u.c.w2[h]  = W2[h];
    }
    __syncthreads();
    {
        const int4* p4 = (const int4*)(packed + base);
        for (int i = tid; i < lq; i += TPS) {
            int4 w = p4[i];
            pk4[i] = w;
            atomicAdd(&u.c.hist[w.x >> RBITS], 1);
            atomicAdd(&u.c.hist[w.y >> RBITS], 1);
            atomicAdd(&u.c.hist[w.z >> RBITS], 1);
            atomicAdd(&u.c.hist[w.w >> RBITS], 1);
        }
        for (int e = (lq << 2) + tid; e < len; e += TPS) {
            int w = packed[base + e];
            u.c.pk[e] = w;
            atomicAdd(&u.c.hist[w >> RBITS], 1);
        }
    }
    __syncthreads();
    const int   myi = bid * BSH + tid;
    const bool  own = (tid < BSH) && (myi < n);
    float  my_d = 0.f;
    float2 my_y = make_float2(0.f, 0.f);
    if (tid < BSH) {
        int cnt = u.c.hist[tid];
        ((float*)u.c.hist)[tid] = 0.f;       // re-zero as phase-4 float acc (same thread)
        if (own) {
            my_d = rsqrtf((float)(1 + cnt)); // +1 self-loop
            float2 xv = x[myi];
            my_y = make_float2(my_d * xv.x, my_d * xv.y);
            y[myi] = my_y;
        }
    }

    grid.sync();   // y globally visible

    // ---------- phase 3: scatter y (edges from LDS), MLP -> t ----------
    for (int i = tid; i < lq; i += TPS) {
        int4 w = pk4[i];
        float2 v; float* sp;
        v = y[w.x & RMASK]; sp = (float*)&u.c.acc[w.x >> RBITS];
        atomicAdd(sp, v.x); atomicAdd(sp + 1, v.y);
        v = y[w.y & RMASK]; sp = (float*)&u.c.acc[w.y >> RBITS];
        atomicAdd(sp, v.x); atomicAdd(sp + 1, v.y);
        v = y[w.z & RMASK]; sp = (float*)&u.c.acc[w.z >> RBITS];
        atomicAdd(sp, v.x); atomicAdd(sp + 1, v.y);
        v = y[w.w & RMASK]; sp = (float*)&u.c.acc[w.w >> RBITS];
        atomicAdd(sp, v.x); atomicAdd(sp + 1, v.y);
    }
    for (int e = (lq << 2) + tid; e < len; e += TPS) {
        int w = u.c.pk[e];
        float2 v = y[w & RMASK];
        float* sp = (float*)&u.c.acc[w >> RBITS];
        atomicAdd(sp, v.x); atomicAdd(sp + 1, v.y);
    }
    __syncthreads();
    float my_t = 0.f;
    if (own) {
        float a0 = my_d * (u.c.acc[tid].x + my_y.x);
        float a1 = my_d * (u.c.acc[tid].y + my_y.y);
        float acc = 0.f;
#pragma unroll
        for (int h = 0; h < 64; ++h) {
            float v = fmaf(a0, u.c.w1a[h], fmaf(a1, u.c.w1b[h], u.c.bb1[h]));
            acc = fmaf(fmaxf(v, 0.f), u.c.w2[h], acc);
        }
        my_t = my_d * acc;
        t[myi] = my_t;
    }

    grid.sync();   // t globally visible

    // ---------- phase 4: scatter t (edges from LDS), out ----------
    float* sacc = (float*)u.c.hist;   // zeroed in phase 2
    for (int i = tid; i < lq; i += TPS) {
        int4 w = pk4[i];
        atomicAdd(&sacc[w.x >> RBITS], t[w.x & RMASK]);
        atomicAdd(&sacc[w.y >> RBITS], t[w.y & RMASK]);
        atomicAdd(&sacc[w.z >> RBITS], t[w.z & RMASK]);
        atomicAdd(&sacc[w.w >> RBITS], t[w.w & RMASK]);
    }
    for (int e = (lq << 2) + tid; e < len; e += TPS) {
        int w = u.c.pk[e];
        atomicAdd(&sacc[w >> RBITS], t[w & RMASK]);
    }
    __syncthreads();
    if (own) out[myi] = fmaf(my_d, sacc[tid] + my_t, B2[0]);
}

// ===================== fallback: exact R14 4-kernel chain =====================

__global__ void __launch_bounds__(TPS)
k_sort(const int* __restrict__ row, const int* __restrict__ col,
       int* __restrict__ gcur, int* __restrict__ packed, int E) {
    __shared__ int fill[NBUCK];
    __shared__ int gb[NBUCK];
    __shared__ int stage[NBUCK * SCAPS];   // 49 KB
    const int tid = threadIdx.x, bid = blockIdx.x;
    for (int i = tid; i < NBUCK; i += TPS) fill[i] = 0;
    __syncthreads();
    const int q = E >> 2;
    const int q0 = (int)((long long)bid * q / SORTB);
    const int q1 = (int)((long long)(bid + 1) * q / SORTB);
    const int4* c4 = (const int4*)col;
    const int4* r4 = (const int4*)row;
    for (int i = q0 + tid; i < q1; i += TPS) {
        int4 c = c4[i], r = r4[i];
        sort_one(c.x, r.x, fill, stage, gcur, packed);
        sort_one(c.y, r.y, fill, stage, gcur, packed);
        sort_one(c.z, r.z, fill, stage, gcur, packed);
        sort_one(c.w, r.w, fill, stage, gcur, packed);
    }
    if (bid == SORTB - 1)
        for (int e = (q << 2) + tid; e < E; e += TPS)
            sort_one(col[e], row[e], fill, stage, gcur, packed);
    __syncthreads();
    for (int b = tid; b < NBUCK; b += TPS)
        gb[b] = b * CAP + atomicAdd(&gcur[b], min(fill[b], SCAPS));
    __syncthreads();
    const int wid = tid >> 6, lane = tid & 63;
    for (int b = wid; b < NBUCK; b += (TPS >> 6)) {
        int cnt = min(fill[b], SCAPS);
        if (lane < cnt) packed[gb[b] + lane] = stage[b * SCAPS + lane];
    }
}

__global__ void __launch_bounds__(TPB)
k_h1(const int* __restrict__ gcur, const int* __restrict__ packed,
     const float2* __restrict__ x, float* __restrict__ dinv,
     float2* __restrict__ y, int n) {
    __shared__ int s[BSH];
    const int b = blockIdx.x;
    if (threadIdx.x < BSH) s[threadIdx.x] = 0;
    __syncthreads();
    const int base = b * CAP;
    const int len = gcur[b];
    const int q = len >> 2;
    const int4* p4 = (const int4*)(packed + base);
    for (int i = threadIdx.x; i < q; i += TPB) {
        int4 w = p4[i];
        atomicAdd(&s[w.x >> RBITS], 1);
        atomicAdd(&s[w.y >> RBITS], 1);
        atomicAdd(&s[w.z >> RBITS], 1);
        atomicAdd(&s[w.w >> RBITS], 1);
    }
    for (int e = (q << 2) + threadIdx.x; e < len; e += TPB)
        atomicAdd(&s[packed[base + e] >> RBITS], 1);
    __syncthreads();
    if (threadIdx.x < BSH) {
        int i = b * BSH + threadIdx.x;
        if (i < n) {
            float d = rsqrtf((float)(1 + s[threadIdx.x]));
            dinv[i] = d;
            float2 xv = x[i];
            y[i] = make_float2(d * xv.x, d * xv.y);
        }
    }
}

__global__ void __launch_bounds__(TPB)
k_sc1(const int* __restrict__ gcur, const int* __restrict__ packed,
      const float2* __restrict__ y, const float* __restrict__ dinv,
      const float* __restrict__ W1, const float* __restrict__ B1,
      const float* __restrict__ W2, float* __restrict__ t, int n) {
    __shared__ float2 s[BSH];
    __shared__ float w1a[64], w1b[64], bb1[64], w2[64];
    if (threadIdx.x >= 256 && threadIdx.x < 320) {
        int h = threadIdx.x - 256;
        w1a[h] = W1[h];
        w1b[h] = W1[64 + h];
        bb1[h] = B1[h];
        w2[h]  = W2[h];
    }
    if (threadIdx.x < BSH) s[threadIdx.x] = make_float2(0.f, 0.f);
    __syncthreads();
    const int b = blockIdx.x;
    const int base = b * CAP;
    const int len = gcur[b];
    const int q = len >> 2;
    const int4* p4 = (const int4*)(packed + base);
    for (int i = threadIdx.x; i < q; i += TPB) {
        int4 w = p4[i];
        float2 v; float* sp;
        v = y[w.x & RMASK]; sp = (float*)&s[w.x >> RBITS];
        atomicAdd(sp, v.x); atomicAdd(sp + 1, v.y);
        v = y[w.y & RMASK]; sp = (float*)&s[w.y >> RBITS];
        atomicAdd(sp, v.x); atomicAdd(sp + 1, v.y);
        v = y[w.z & RMASK]; sp = (float*)&s[w.z >> RBITS];
        atomicAdd(sp, v.x); atomicAdd(sp + 1, v.y);
        v = y[w.w & RMASK]; sp = (float*)&s[w.w >> RBITS];
        atomicAdd(sp, v.x); atomicAdd(sp + 1, v.y);
    }
    for (int e = (q << 2) + threadIdx.x; e < len; e += TPB) {
        int w = packed[base + e];
        float2 v = y[w & RMASK];
        float* sp = (float*)&s[w >> RBITS];
        atomicAdd(sp, v.x); atomicAdd(sp + 1, v.y);
    }
    __syncthreads();
    if (threadIdx.x < BSH) {
        int i = b * BSH + threadIdx.x;
        if (i < n) {
            float d = dinv[i];
            float2 yv = y[i];
            float a0 = d * (s[threadIdx.x].x + yv.x);
            float a1 = d * (s[threadIdx.x].y + yv.y);
            float acc = 0.f;
#pragma unroll
            for (int h = 0; h < 64; ++h) {
                float v = fmaf(a0, w1a[h], fmaf(a1, w1b[h], bb1[h]));
                acc = fmaf(fmaxf(v, 0.f), w2[h], acc);
            }
            t[i] = d * acc;
        }
    }
}

__global__ void __launch_bounds__(TPB)
k_sc2(const int* __restrict__ gcur, const int* __restrict__ packed,
      const float* __restrict__ t, const float* __restrict__ dinv,
      const float* __restrict__ B2, float* __restrict__ out, int n) {
    __shared__ float s[BSH];
    const int b = blockIdx.x;
    if (threadIdx.x < BSH) s[threadIdx.x] = 0.f;
    __syncthreads();
    const int base = b * CAP;
    const int len = gcur[b];
    const int q = len >> 2;
    const int4* p4 = (const int4*)(packed + base);
    for (int i = threadIdx.x; i < q; i += TPB) {
        int4 w = p4[i];
        atomicAdd(&s[w.x >> RBITS], t[w.x & RMASK]);
        atomicAdd(&s[w.y >> RBITS], t[w.y & RMASK]);
        atomicAdd(&s[w.z >> RBITS], t[w.z & RMASK]);
        atomicAdd(&s[w.w >> RBITS], t[w.w & RMASK]);
    }
    for (int e = (q << 2) + threadIdx.x; e < len; e += TPB) {
        int w = packed[base + e];
        atomicAdd(&s[w >> RBITS], t[w & RMASK]);
    }
    __syncthreads();
    if (threadIdx.x < BSH) {
        int i = b * BSH + threadIdx.x;
        if (i < n) out[i] = fmaf(dinv[i], s[threadIdx.x] + t[i], B2[0]);
    }
}

extern "C" void kernel_launch(void* const* d_in, const int* in_sizes, int n_in,
                              void* d_out, int out_size, void* d_ws, size_t ws_size,
                              hipStream_t stream) {
    const float* x  = (const float*)d_in[0];
    const int*   ei = (const int*)d_in[1];
    const float* W1 = (const float*)d_in[2];
    const float* B1 = (const float*)d_in[3];
    const float* W2 = (const float*)d_in[4];
    const float* B2 = (const float*)d_in[5];
    float* out = (float*)d_out;

    int n = in_sizes[0] / 2;      // 100,000
    int E = in_sizes[1] / 2;      // 3,200,000
    const int* row = ei;
    const int* col = ei + E;

    // ws: dinv[n] (fallback only) | y[n](f2) | t[n] | gcur[512] | packed[~13.8MB]
    char* ws = (char*)d_ws;
    size_t off = 0;
    float*  dinv = (float*)(ws + off);  off += (size_t)n * 4;
    float2* y    = (float2*)(ws + off); off += (size_t)n * 8;
    float*  t    = (float*)(ws + off);  off += (size_t)n * 4;
    off = (off + 255) & ~(size_t)255;
    int* gcur    = (int*)(ws + off);    off += (size_t)NBUCK * 4;
    off = (off + 255) & ~(size_t)255;
    int* packed  = (int*)(ws + off);

    hipMemsetAsync(gcur, 0, (size_t)NBUCK * 4, stream);   // relative cursors

    const float2* x2 = (const float2*)x;
    void* args[] = {(void*)&row, (void*)&col, (void*)&x2,
                    (void*)&W1, (void*)&B1, (void*)&W2, (void*)&B2,
                    (void*)&gcur, (void*)&packed,
                    (void*)&y, (void*)&t, (void*)&out, (void*)&E, (void*)&n};
    hipError_t err = hipLaunchCooperativeKernel((const void*)k_fused,
                                                dim3(SORTB), dim3(TPS),
                                                args, 0, stream);
    if (err != hipSuccess) {
        // fallback: proven R14 chain
        k_sort<<<SORTB, TPS, 0, stream>>>(row, col, gcur, packed, E);
        k_h1  <<<NBUCK, TPB, 0, stream>>>(gcur, packed, x2, dinv, y, n);
        k_sc1 <<<NBUCK, TPB, 0, stream>>>(gcur, packed, y, dinv, W1, B1, W2, t, n);
        k_sc2 <<<NBUCK, TPB, 0, stream>>>(gcur, packed, t, dinv, B2, out, n);
    }
}

// Round 3
// 163.414 us; speedup vs baseline: 2.1104x; 2.1104x over previous
//
#include <hip/hip_runtime.h>

// GCN 2-layer, N=100k, E=3.2M, IN=2, HID=64, OUT=1 (all float32).
// R17 = exact R14 4-kernel chain (158.8us proven) + three latency/contention
// fixes inside the scatter kernels:
//  - 4x replicated LDS accumulators (per-wave replica (tid>>6)&3) in
//    k_h1/k_sc1/k_sc2: quarters same-address LDS-atomic serialization
//  - software-pipelined packed loops (prefetch next int4, group all gathers
//    before atomics) for deeper per-wave memory pipelines
//  - nontemporal loads/stores on all streaming traffic (edges, packed) so
//    the y (800KB) / t (400KB) gather working sets stay L2-resident
// R15 lesson: no random global atomics (100MB HBM write). R16 lesson: no
// cooperative grid.sync (~30us each vs ~4us launch boundary) -- 4-launch
// structure is dependency-minimal and stays.

#define NBUCK 512
#define BSH   196        // nodes per bucket (512*196 = 100352 >= n)
#define RBITS 17         // row bits (n < 131072)
#define RMASK ((1 << RBITS) - 1)
#define CAP   6752       // packed ints per bucket (mean 6250, +6.3 sigma), %4==0
#define SORTB 512
#define SCAPS 24         // staging per (block,bucket): mean 12.2, +3.4 sigma
#define TPS   1024
#define TPB   1024
#define NREP  4          // LDS accumulator replicas

typedef int i4 __attribute__((ext_vector_type(4)));

__device__ __forceinline__ void sort_one(int c, int r, int* fill, int* stage,
                                         int* __restrict__ gcur,
                                         int* __restrict__ packed) {
    int b = (int)((unsigned)c / (unsigned)BSH);   // magic-mul div by 196
    int l = c - b * BSH;
    int w = (l << RBITS) | r;
    int p = atomicAdd(&fill[b], 1);
    if (p < SCAPS) stage[b * SCAPS + p] = w;
    else __builtin_nontemporal_store(w, &packed[b * CAP + atomicAdd(&gcur[b], 1)]);
}

// staged counting sort by dest bucket: packed[b-region] gets ((lcol<<17)|row)
__global__ void __launch_bounds__(TPS)
k_sort(const int* __restrict__ row, const int* __restrict__ col,
       int* __restrict__ gcur, int* __restrict__ packed, int E) {
    __shared__ int fill[NBUCK];
    __shared__ int gb[NBUCK];
    __shared__ int stage[NBUCK * SCAPS];   // 49 KB
    const int tid = threadIdx.x, bid = blockIdx.x;
    for (int i = tid; i < NBUCK; i += TPS) fill[i] = 0;
    __syncthreads();
    const int q = E >> 2;
    const int q0 = (int)((long long)bid * q / SORTB);
    const int q1 = (int)((long long)(bid + 1) * q / SORTB);
    const i4* c4 = (const i4*)col;
    const i4* r4 = (const i4*)row;
    for (int i = q0 + tid; i < q1; i += TPS) {
        i4 c = __builtin_nontemporal_load(c4 + i);
        i4 r = __builtin_nontemporal_load(r4 + i);
        sort_one(c.x, r.x, fill, stage, gcur, packed);
        sort_one(c.y, r.y, fill, stage, gcur, packed);
        sort_one(c.z, r.z, fill, stage, gcur, packed);
        sort_one(c.w, r.w, fill, stage, gcur, packed);
    }
    if (bid == SORTB - 1)   // tail if E % 4 != 0
        for (int e = (q << 2) + tid; e < E; e += TPS)
            sort_one(col[e], row[e], fill, stage, gcur, packed);
    __syncthreads();
    for (int b = tid; b < NBUCK; b += TPS)
        gb[b] = b * CAP + atomicAdd(&gcur[b], min(fill[b], SCAPS));
    __syncthreads();
    const int wid = tid >> 6, lane = tid & 63;
    for (int b = wid; b < NBUCK; b += (TPS >> 6)) {  // per-wave coalesced copy-out
        int cnt = min(fill[b], SCAPS);               // cnt <= 24 < wave
        if (lane < cnt)
            __builtin_nontemporal_store(stage[b * SCAPS + lane], &packed[gb[b] + lane]);
    }
}

// hist + epilogue: deg -> dinv; y = dinv*x   (one block = one whole bucket)
__global__ void __launch_bounds__(TPB)
k_h1(const int* __restrict__ gcur, const int* __restrict__ packed,
     const float2* __restrict__ x, float* __restrict__ dinv,
     float2* __restrict__ y, int n) {
    __shared__ int hs[NREP][BSH];
    const int b = blockIdx.x, tid = threadIdx.x;
    if (tid < BSH) { hs[0][tid] = 0; hs[1][tid] = 0; hs[2][tid] = 0; hs[3][tid] = 0; }
    __syncthreads();
    int* hr = hs[(tid >> 6) & (NREP - 1)];
    const int base = b * CAP;
    const int len = gcur[b];
    const int q = len >> 2;
    const i4* p4 = (const i4*)(packed + base);
#define H1_PROC(w) { \
    atomicAdd(&hr[(w).x >> RBITS], 1); \
    atomicAdd(&hr[(w).y >> RBITS], 1); \
    atomicAdd(&hr[(w).z >> RBITS], 1); \
    atomicAdd(&hr[(w).w >> RBITS], 1); }
    int i = tid;
    if (i < q) {
        i4 w = __builtin_nontemporal_load(p4 + i);
        for (i += TPB; i < q; i += TPB) {
            i4 wn = __builtin_nontemporal_load(p4 + i);
            H1_PROC(w);
            w = wn;
        }
        H1_PROC(w);
    }
    for (int e = (q << 2) + tid; e < len; e += TPB)
        atomicAdd(&hr[packed[base + e] >> RBITS], 1);
    __syncthreads();
    if (tid < BSH) {
        int idx = b * BSH + tid;
        if (idx < n) {
            int cnt = hs[0][tid] + hs[1][tid] + hs[2][tid] + hs[3][tid];
            float d = rsqrtf((float)(1 + cnt));   // +1 self-loop
            dinv[idx] = d;
            float2 xv = x[idx];
            y[idx] = make_float2(d * xv.x, d * xv.y);
        }
    }
}

// s1 + MLP epilogue: agg = sum y[row]; t = dinv*(relu((dinv*(agg+y))@W1+b1)@W2)
__global__ void __launch_bounds__(TPB)
k_sc1(const int* __restrict__ gcur, const int* __restrict__ packed,
      const float2* __restrict__ y, const float* __restrict__ dinv,
      const float* __restrict__ W1, const float* __restrict__ B1,
      const float* __restrict__ W2, float* __restrict__ t, int n) {
    __shared__ float2 s[NREP][BSH];
    __shared__ float w1a[64], w1b[64], bb1[64], w2[64];
    const int b = blockIdx.x, tid = threadIdx.x;
    if (tid >= 256 && tid < 320) {
        int h = tid - 256;
        w1a[h] = W1[h];
        w1b[h] = W1[64 + h];
        bb1[h] = B1[h];
        w2[h]  = W2[h];
    }
    if (tid < BSH) {
        s[0][tid] = make_float2(0.f, 0.f);
        s[1][tid] = make_float2(0.f, 0.f);
        s[2][tid] = make_float2(0.f, 0.f);
        s[3][tid] = make_float2(0.f, 0.f);
    }
    __syncthreads();
    float2* sr = s[(tid >> 6) & (NREP - 1)];
    const int base = b * CAP;
    const int len = gcur[b];
    const int q = len >> 2;
    const i4* p4 = (const i4*)(packed + base);
#define SC1_PROC(w) { \
    float2 v0 = y[(w).x & RMASK], v1 = y[(w).y & RMASK]; \
    float2 v2 = y[(w).z & RMASK], v3 = y[(w).w & RMASK]; \
    float* sp; \
    sp = (float*)&sr[(w).x >> RBITS]; atomicAdd(sp, v0.x); atomicAdd(sp + 1, v0.y); \
    sp = (float*)&sr[(w).y >> RBITS]; atomicAdd(sp, v1.x); atomicAdd(sp + 1, v1.y); \
    sp = (float*)&sr[(w).z >> RBITS]; atomicAdd(sp, v2.x); atomicAdd(sp + 1, v2.y); \
    sp = (float*)&sr[(w).w >> RBITS]; atomicAdd(sp, v3.x); atomicAdd(sp + 1, v3.y); }
    int i = tid;
    if (i < q) {
        i4 w = __builtin_nontemporal_load(p4 + i);
        for (i += TPB; i < q; i += TPB) {
            i4 wn = __builtin_nontemporal_load(p4 + i);
            SC1_PROC(w);
            w = wn;
        }
        SC1_PROC(w);
    }
    for (int e = (q << 2) + tid; e < len; e += TPB) {
        int w = packed[base + e];
        float2 v = y[w & RMASK];
        float* sp = (float*)&sr[w >> RBITS];
        atomicAdd(sp, v.x); atomicAdd(sp + 1, v.y);
    }
    __syncthreads();
    if (tid < BSH) {
        int idx = b * BSH + tid;
        if (idx < n) {
            float d = dinv[idx];
            float2 yv = y[idx];
            float sx = s[0][tid].x + s[1][tid].x + s[2][tid].x + s[3][tid].x;
            float sy = s[0][tid].y + s[1][tid].y + s[2][tid].y + s[3][tid].y;
            float a0 = d * (sx + yv.x);
            float a1 = d * (sy + yv.y);
            float acc = 0.f;
#pragma unroll
            for (int h = 0; h < 64; ++h) {
                float v = fmaf(a0, w1a[h], fmaf(a1, w1b[h], bb1[h]));
                acc = fmaf(fmaxf(v, 0.f), w2[h], acc);
            }
            t[idx] = d * acc;
        }
    }
}

// s2 + output epilogue: o = sum t[row]; out = dinv*(o + t_self) + b2
__global__ void __launch_bounds__(TPB)
k_sc2(const int* __restrict__ gcur, const int* __restrict__ packed,
      const float* __restrict__ t, const float* __restrict__ dinv,
      const float* __restrict__ B2, float* __restrict__ out, int n) {
    __shared__ float s[NREP][BSH];
    const int b = blockIdx.x, tid = threadIdx.x;
    if (tid < BSH) { s[0][tid] = 0.f; s[1][tid] = 0.f; s[2][tid] = 0.f; s[3][tid] = 0.f; }
    __syncthreads();
    float* sr = s[(tid >> 6) & (NREP - 1)];
    const int base = b * CAP;
    const int len = gcur[b];
    const int q = len >> 2;
    const i4* p4 = (const i4*)(packed + base);
#define SC2_PROC(w) { \
    float v0 = t[(w).x & RMASK], v1 = t[(w).y & RMASK]; \
    float v2 = t[(w).z & RMASK], v3 = t[(w).w & RMASK]; \
    atomicAdd(&sr[(w).x >> RBITS], v0); \
    atomicAdd(&sr[(w).y >> RBITS], v1); \
    atomicAdd(&sr[(w).z >> RBITS], v2); \
    atomicAdd(&sr[(w).w >> RBITS], v3); }
    int i = tid;
    if (i < q) {
        i4 w = __builtin_nontemporal_load(p4 + i);
        for (i += TPB; i < q; i += TPB) {
            i4 wn = __builtin_nontemporal_load(p4 + i);
            SC2_PROC(w);
            w = wn;
        }
        SC2_PROC(w);
    }
    for (int e = (q << 2) + tid; e < len; e += TPB) {
        int w = packed[base + e];
        atomicAdd(&sr[w >> RBITS], t[w & RMASK]);
    }
    __syncthreads();
    if (tid < BSH) {
        int idx = b * BSH + tid;
        if (idx < n) {
            float ssum = s[0][tid] + s[1][tid] + s[2][tid] + s[3][tid];
            out[idx] = fmaf(dinv[idx], ssum + t[idx], B2[0]);
        }
    }
}

extern "C" void kernel_launch(void* const* d_in, const int* in_sizes, int n_in,
                              void* d_out, int out_size, void* d_ws, size_t ws_size,
                              hipStream_t stream) {
    const float* x  = (const float*)d_in[0];
    const int*   ei = (const int*)d_in[1];
    const float* W1 = (const float*)d_in[2];
    const float* B1 = (const float*)d_in[3];
    const float* W2 = (const float*)d_in[4];
    const float* B2 = (const float*)d_in[5];
    float* out = (float*)d_out;

    const int n = in_sizes[0] / 2;      // 100,000
    const int E = in_sizes[1] / 2;      // 3,200,000
    const int* row = ei;
    const int* col = ei + E;

    // ws: dinv[n] | y[n](f2) | t[n] | gcur[512] | packed[512*CAP ~13.8MB]
    char* ws = (char*)d_ws;
    size_t off = 0;
    float*  dinv = (float*)(ws + off);  off += (size_t)n * 4;
    float2* y    = (float2*)(ws + off); off += (size_t)n * 8;
    float*  t    = (float*)(ws + off);  off += (size_t)n * 4;
    off = (off + 255) & ~(size_t)255;
    int* gcur    = (int*)(ws + off);    off += (size_t)NBUCK * 4;
    off = (off + 255) & ~(size_t)255;
    int* packed  = (int*)(ws + off);

    hipMemsetAsync(gcur, 0, (size_t)NBUCK * 4, stream);   // relative cursors
    k_sort<<<SORTB, TPS, 0, stream>>>(row, col, gcur, packed, E);
    k_h1  <<<NBUCK, TPB, 0, stream>>>(gcur, packed, (const float2*)x, dinv, y, n);
    k_sc1 <<<NBUCK, TPB, 0, stream>>>(gcur, packed, y, dinv, W1, B1, W2, t, n);
    k_sc2 <<<NBUCK, TPB, 0, stream>>>(gcur, packed, t, dinv, B2, out, n);
}